// Round 1
// baseline (1833.542 us; speedup 1.0000x reference)
//
#include <hip/hip_runtime.h>
#include <math.h>

// Problem constants (fixed by setup_inputs)
#define BQ    4
#define NTOT  13125          // 100*100 + 50*50 + 25*25
#define DD    256
#define NHH   8
#define DHH   32
#define LL    3
#define PP    4
#define FFD   1024
#define EPSLN 1e-5f
#define MROWS (BQ * NTOT)    // 52500

// GEMM tiling
#define BM 64
#define BN 64
#define BK 16
#define LDA (BM + 4)
#define LDB (BN + 4)

enum { EPI_PLAIN = 0, EPI_VAL = 1, EPI_GELU = 2 };

// ---------------------------------------------------------------------------
// Tiled fp32 GEMM: C = A[M,K] @ W[K,N] + bias, with epilogue variants.
// EPI_VAL: output row remapped to b*NTOT + loff + (row % Nl), out stride 256.
// ---------------------------------------------------------------------------
template <int EPI>
__launch_bounds__(256)
__global__ void gemm_k(const float* __restrict__ A, const float* __restrict__ W,
                       const float* __restrict__ bias, float* __restrict__ C,
                       int M, int N, int K, int Nl, int loff) {
    __shared__ float As[BK][LDA];
    __shared__ float Bs[BK][LDB];

    const int m0 = blockIdx.x * BM;
    const int n0 = blockIdx.y * BN;
    const int tid = threadIdx.x;
    const int tm = tid >> 4;        // 0..15
    const int tn = tid & 15;        // 0..15

    const int la_m = tid >> 2;          // 0..63
    const int la_k = (tid & 3) * 4;     // 0,4,8,12
    const int lb_k = tid >> 4;          // 0..15
    const int lb_n = (tid & 15) * 4;    // 0..60

    float acc[4][4];
#pragma unroll
    for (int i = 0; i < 4; i++)
#pragma unroll
        for (int j = 0; j < 4; j++) acc[i][j] = 0.f;

    for (int k0 = 0; k0 < K; k0 += BK) {
        // A tile: 64 rows x 16 k
        float4 av = make_float4(0.f, 0.f, 0.f, 0.f);
        int gm = m0 + la_m;
        if (gm < M) av = *(const float4*)&A[(size_t)gm * K + k0 + la_k];
        As[la_k + 0][la_m] = av.x;
        As[la_k + 1][la_m] = av.y;
        As[la_k + 2][la_m] = av.z;
        As[la_k + 3][la_m] = av.w;
        // B tile: 16 k x 64 cols
        float4 bv = make_float4(0.f, 0.f, 0.f, 0.f);
        int gn = n0 + lb_n;
        if (gn < N) bv = *(const float4*)&W[(size_t)(k0 + lb_k) * N + gn];
        *(float4*)&Bs[lb_k][lb_n] = bv;
        __syncthreads();

#pragma unroll
        for (int k = 0; k < BK; k++) {
            float4 a4 = *(const float4*)&As[k][tm * 4];
            float4 b4 = *(const float4*)&Bs[k][tn * 4];
            float ar[4] = {a4.x, a4.y, a4.z, a4.w};
            float br[4] = {b4.x, b4.y, b4.z, b4.w};
#pragma unroll
            for (int i = 0; i < 4; i++)
#pragma unroll
                for (int j = 0; j < 4; j++) acc[i][j] += ar[i] * br[j];
        }
        __syncthreads();
    }

#pragma unroll
    for (int i = 0; i < 4; i++) {
        int gm = m0 + tm * 4 + i;
        if (gm >= M) continue;
        size_t orow;
        if (EPI == EPI_VAL) {
            int b = gm / Nl;
            int nl = gm - b * Nl;
            orow = (size_t)b * NTOT + loff + nl;
        } else {
            orow = (size_t)gm;
        }
#pragma unroll
        for (int j = 0; j < 4; j++) {
            int gn = n0 + tn * 4 + j;
            if (gn >= N) continue;
            float v = acc[i][j] + bias[gn];
            if (EPI == EPI_GELU) v = 0.5f * v * (1.f + erff(v * 0.70710678118f));
            size_t ostride = (EPI == EPI_VAL) ? (size_t)DD : (size_t)N;
            C[orow * ostride + gn] = v;
        }
    }
}

// ---------------------------------------------------------------------------
// ref = sigmoid(query @ Wref + bref), Wref [256,2]. One wave per row.
// ---------------------------------------------------------------------------
__launch_bounds__(256)
__global__ void ref_k(const float* __restrict__ Q, const float* __restrict__ Wref,
                      const float* __restrict__ bref, float* __restrict__ refb) {
    int wid = threadIdx.x >> 6;
    int lane = threadIdx.x & 63;
    int row = blockIdx.x * 4 + wid;
    if (row >= MROWS) return;
    float4 q = *(const float4*)&Q[(size_t)row * DD + lane * 4];
    // Wref row-major [256][2]; 4 ks -> 8 consecutive floats
    float4 w01 = *(const float4*)&Wref[lane * 8];
    float4 w23 = *(const float4*)&Wref[lane * 8 + 4];
    float s0 = q.x * w01.x + q.y * w01.z + q.z * w23.x + q.w * w23.z;
    float s1 = q.x * w01.y + q.y * w01.w + q.z * w23.y + q.w * w23.w;
#pragma unroll
    for (int m = 32; m >= 1; m >>= 1) {
        s0 += __shfl_xor(s0, m);
        s1 += __shfl_xor(s1, m);
    }
    if (lane == 0) {
        float v0 = s0 + bref[0], v1 = s1 + bref[1];
        refb[(size_t)row * 2 + 0] = 1.f / (1.f + expf(-v0));
        refb[(size_t)row * 2 + 1] = 1.f / (1.f + expf(-v1));
    }
}

// ---------------------------------------------------------------------------
// In-place softmax over groups of 12 (L*P) per (b,n,h).
// ---------------------------------------------------------------------------
__launch_bounds__(256)
__global__ void softmax12_k(float* __restrict__ aw) {
    int rh = blockIdx.x * 256 + threadIdx.x;   // (b*N + n)*NH + h
    if (rh >= MROWS * NHH) return;
    float* p = aw + (size_t)rh * 12;
    float v[12], mx = -1e30f;
#pragma unroll
    for (int i = 0; i < 12; i++) { v[i] = p[i]; mx = fmaxf(mx, v[i]); }
    float s = 0.f;
#pragma unroll
    for (int i = 0; i < 12; i++) { v[i] = expf(v[i] - mx); s += v[i]; }
    float inv = 1.f / s;
#pragma unroll
    for (int i = 0; i < 12; i++) p[i] = v[i] * inv;
}

// ---------------------------------------------------------------------------
// Deformable sampling: out[b,n,h*32+d] = sum_{l,p} aw * bilinear(val).
// Block = 256 threads = 8 heads x 32 dims. Grid = (NTOT, B).
// ---------------------------------------------------------------------------
__launch_bounds__(256)
__global__ void sample_k(const float* __restrict__ val, const float* __restrict__ off,
                         const float* __restrict__ aw, const float* __restrict__ refb,
                         float* __restrict__ out) {
    const int n = blockIdx.x, b = blockIdx.y;
    const int tid = threadIdx.x;
    __shared__ float sw[96][4];
    __shared__ int sidx[96][4];

    const size_t bn = (size_t)b * NTOT + n;
    if (tid < 96) {
        const int lp = tid % 12;
        const int l = lp >> 2;
        int Hl, Wl, loff;
        if (l == 0)      { Hl = 100; Wl = 100; loff = 0; }
        else if (l == 1) { Hl = 50;  Wl = 50;  loff = 10000; }
        else             { Hl = 25;  Wl = 25;  loff = 12500; }
        float ox = off[bn * 192 + tid * 2 + 0];
        float oy = off[bn * 192 + tid * 2 + 1];
        float a  = aw[bn * 96 + tid];
        float rx = refb[bn * 2 + 0];
        float ry = refb[bn * 2 + 1];
        // x = (rx + ox/Wl)*Wl - 0.5
        float x = rx * (float)Wl + ox - 0.5f;
        float y = ry * (float)Hl + oy - 0.5f;
        x = fminf(fmaxf(x, -1e4f), 1e4f);
        y = fminf(fmaxf(y, -1e4f), 1e4f);
        float x0f = floorf(x), y0f = floorf(y);
        float lx = x - x0f, ly = y - y0f;
        int x0 = (int)x0f, y0 = (int)y0f;
#pragma unroll
        for (int c = 0; c < 4; c++) {
            int xi = x0 + (c & 1);
            int yi = y0 + (c >> 1);
            bool ok = (xi >= 0) && (xi < Wl) && (yi >= 0) && (yi < Hl);
            int xc = min(max(xi, 0), Wl - 1);
            int yc = min(max(yi, 0), Hl - 1);
            sidx[tid][c] = b * NTOT + loff + yc * Wl + xc;
            float wgt = ((c & 1) ? lx : 1.f - lx) * ((c >> 1) ? ly : 1.f - ly);
            sw[tid][c] = ok ? a * wgt : 0.f;
        }
    }
    __syncthreads();

    const int h = tid >> 5, d = tid & 31;
    float acc = 0.f;
#pragma unroll
    for (int lp = 0; lp < 12; lp++) {
        int s = h * 12 + lp;
#pragma unroll
        for (int c = 0; c < 4; c++) {
            float w = sw[s][c];
            if (w != 0.f) acc += w * val[(size_t)sidx[s][c] * DD + h * DHH + d];
        }
    }
    out[bn * DD + tid] = acc;
}

// ---------------------------------------------------------------------------
// out = LN(a + r) * g + be.  One wave per row of 256. Block = 4 waves.
// ---------------------------------------------------------------------------
__launch_bounds__(256)
__global__ void addln_k(const float* __restrict__ a, const float* __restrict__ r,
                        const float* __restrict__ g, const float* __restrict__ be,
                        float* __restrict__ out) {
    int wid = threadIdx.x >> 6;
    int lane = threadIdx.x & 63;
    int row = blockIdx.x * 4 + wid;
    if (row >= MROWS) return;
    float4 xa = *(const float4*)&a[(size_t)row * DD + lane * 4];
    float4 xr = *(const float4*)&r[(size_t)row * DD + lane * 4];
    float x0 = xa.x + xr.x, x1 = xa.y + xr.y, x2 = xa.z + xr.z, x3 = xa.w + xr.w;
    float s = x0 + x1 + x2 + x3;
    float sq = x0 * x0 + x1 * x1 + x2 * x2 + x3 * x3;
#pragma unroll
    for (int m = 32; m >= 1; m >>= 1) {
        s += __shfl_xor(s, m);
        sq += __shfl_xor(sq, m);
    }
    float mean = s * (1.f / DD);
    float var = sq * (1.f / DD) - mean * mean;
    float rs = rsqrtf(var + EPSLN);
    float4 gg = *(const float4*)&g[lane * 4];
    float4 bb = *(const float4*)&be[lane * 4];
    float4 o;
    o.x = (x0 - mean) * rs * gg.x + bb.x;
    o.y = (x1 - mean) * rs * gg.y + bb.y;
    o.z = (x2 - mean) * rs * gg.z + bb.z;
    o.w = (x3 - mean) * rs * gg.w + bb.w;
    *(float4*)&out[(size_t)row * DD + lane * 4] = o;
}

// ---------------------------------------------------------------------------
extern "C" void kernel_launch(void* const* d_in, const int* in_sizes, int n_in,
                              void* d_out, int out_size, void* d_ws, size_t ws_size,
                              hipStream_t stream) {
    const float* query = (const float*)d_in[0];
    const float* p3    = (const float*)d_in[1];
    const float* p4    = (const float*)d_in[2];
    const float* p5    = (const float*)d_in[3];
    const float* Wv    = (const float*)d_in[4];
    const float* bv    = (const float*)d_in[5];
    const float* Woff  = (const float*)d_in[6];
    const float* boff  = (const float*)d_in[7];
    const float* Wattn = (const float*)d_in[8];
    const float* battn = (const float*)d_in[9];
    const float* Wref  = (const float*)d_in[10];
    const float* bref  = (const float*)d_in[11];
    const float* Wo    = (const float*)d_in[12];
    const float* bo    = (const float*)d_in[13];
    const float* W1    = (const float*)d_in[14];
    const float* b1    = (const float*)d_in[15];
    const float* W2    = (const float*)d_in[16];
    const float* b2    = (const float*)d_in[17];
    const float* g1    = (const float*)d_in[18];
    const float* be1   = (const float*)d_in[19];
    const float* g2    = (const float*)d_in[20];
    const float* be2   = (const float*)d_in[21];
    float* outp = (float*)d_out;

    // workspace layout (floats)
    float* ws = (float*)d_ws;
    float* offb  = ws;                      // 52500*192 = 10,080,000
    float* awb   = offb + 10080000;         // 52500*96  =  5,040,000
    float* refb  = awb + 5040000;           //    105,008 (padded)
    float* valb  = refb + 105008;           // 52500*256 = 13,440,000
    float* sampb = valb + 13440000;         // 13,440,000
    float* hidb  = sampb + 13440000;        // 13125*1024 = 13,440,000
    // total 55,545,008 floats = 222.2 MB

    const int mg = (MROWS + BM - 1) / BM;   // 821

    // 1) off = query @ Woff + boff   [52500,192]
    gemm_k<EPI_PLAIN><<<dim3(mg, 3), 256, 0, stream>>>(query, Woff, boff, offb,
                                                       MROWS, 192, 256, 0, 0);
    // 2) attn logits = query @ Wattn + battn   [52500,96]
    gemm_k<EPI_PLAIN><<<dim3(mg, 2), 256, 0, stream>>>(query, Wattn, battn, awb,
                                                       MROWS, 96, 256, 0, 0);
    // 3) ref = sigmoid(query @ Wref + bref)
    ref_k<<<dim3((MROWS + 3) / 4), 256, 0, stream>>>(query, Wref, bref, refb);
    // 4) softmax over 12 in place
    softmax12_k<<<dim3((MROWS * NHH + 255) / 256), 256, 0, stream>>>(awb);
    // 5-7) value projection per level into valb (row-remapped)
    gemm_k<EPI_VAL><<<dim3((40000 + BM - 1) / BM, 4), 256, 0, stream>>>(
        p3, Wv, bv, valb, 40000, 256, 256, 10000, 0);
    gemm_k<EPI_VAL><<<dim3((10000 + BM - 1) / BM, 4), 256, 0, stream>>>(
        p4, Wv, bv, valb, 10000, 256, 256, 2500, 10000);
    gemm_k<EPI_VAL><<<dim3((2500 + BM - 1) / BM, 4), 256, 0, stream>>>(
        p5, Wv, bv, valb, 2500, 256, 256, 625, 12500);
    // 8) deformable sampling -> sampb
    sample_k<<<dim3(NTOT, BQ), 256, 0, stream>>>(valb, offb, awb, refb, sampb);
    // 9) attn_out = sampb @ Wo + bo -> valb (reuse)
    gemm_k<EPI_PLAIN><<<dim3(mg, 4), 256, 0, stream>>>(sampb, Wo, bo, valb,
                                                       MROWS, 256, 256, 0, 0);
    // 10) q = LN(query + attn_out) -> sampb (reuse)
    addln_k<<<dim3(MROWS / 4), 256, 0, stream>>>(query, valb, g1, be1, sampb);
    // 11) FFN, chunked per b: hid = gelu(q @ W1 + b1); ffn = hid @ W2 + b2 -> valb
    for (int b = 0; b < BQ; b++) {
        const float* qc = sampb + (size_t)b * NTOT * DD;
        float* fc = valb + (size_t)b * NTOT * DD;
        gemm_k<EPI_GELU><<<dim3((NTOT + BM - 1) / BM, FFD / BN), 256, 0, stream>>>(
            qc, W1, b1, hidb, NTOT, FFD, 256, 0, 0);
        gemm_k<EPI_PLAIN><<<dim3((NTOT + BM - 1) / BM, 4), 256, 0, stream>>>(
            hidb, W2, b2, fc, NTOT, 256, FFD, 0, 0);
    }
    // 12) out = LN(q + ffn)
    addln_k<<<dim3(MROWS / 4), 256, 0, stream>>>(sampb, valb, g2, be2, outp);
}

// Round 2
// 970.253 us; speedup vs baseline: 1.8898x; 1.8898x over previous
//
#include <hip/hip_runtime.h>
#include <math.h>

// Problem constants
#define BQ    4
#define NTOT  13125
#define DD    256
#define NHH   8
#define DHH   32
#define FFD   1024
#define EPSLN 1e-5f
#define MROWS (BQ * NTOT)        // 52500
#define MPAD  52608              // 411*128
#define NCHUNK 13125
#define NCHUNK_PAD 13184         // 103*128

typedef __bf16 bf16_t;
typedef bf16_t bf16x8 __attribute__((ext_vector_type(8)));
typedef float floatx4 __attribute__((ext_vector_type(4)));

__device__ __forceinline__ unsigned short f2bf(float f) {
    unsigned u = __float_as_uint(f);
    return (unsigned short)((u + 0x7FFFu + ((u >> 16) & 1u)) >> 16);
}
__device__ __forceinline__ float bf2f(unsigned short h) {
    return __uint_as_float(((unsigned)h) << 16);
}

typedef const __attribute__((address_space(1))) unsigned int* gptr_t;
typedef __attribute__((address_space(3))) unsigned int* lptr_t;
__device__ __forceinline__ void gld16(const void* g, void* l) {
    __builtin_amdgcn_global_load_lds((gptr_t)g, (lptr_t)l, 16, 0, 0);
}

enum { EPI_PLAIN = 0, EPI_VAL = 1, EPI_GELU = 2 };

// ---------------------------------------------------------------------------
// bf16 MFMA GEMM, m97 structure. A [Mpad,K] bf16 row-major; Bt [Npad,K] bf16
// (transposed weight). 128x128 tile, BK=32, 4 waves, 4x4 acc of 16x16 mfma.
// ---------------------------------------------------------------------------
template <int EPI, typename OutT>
__launch_bounds__(256)
__global__ void mm_k(const unsigned short* __restrict__ A,
                     const unsigned short* __restrict__ Bt,
                     const float* __restrict__ bias, OutT* __restrict__ C,
                     int M, int K, int Nout, int ldc, int Mstore, int Nl, int loff) {
    __shared__ __align__(16) unsigned short As[128 * 32];
    __shared__ __align__(16) unsigned short Bs[128 * 32];

    const int tid = threadIdx.x;
    const int m0 = blockIdx.x * 128;
    const int n0 = blockIdx.y * 128;
    const int w = tid >> 6, lane = tid & 63;
    const int q = lane >> 4, l15 = lane & 15;
    const int wm = (w & 1) * 64, wn = (w >> 1) * 64;

    const int sr = tid >> 2;          // staging row 0..63
    const int sk = (tid & 3) * 8;     // staging k offset

    const unsigned short* Ag = A + (size_t)(m0 + sr) * K + sk;
    const unsigned short* Bg = Bt + (size_t)(n0 + sr) * K + sk;
    char* AsB = (char*)As;
    char* BsB = (char*)Bs;

    floatx4 acc[4][4];
#pragma unroll
    for (int t = 0; t < 4; t++)
#pragma unroll
        for (int u = 0; u < 4; u++) {
            floatx4 z = {0.f, 0.f, 0.f, 0.f};
            acc[t][u] = z;
        }

    for (int k0 = 0; k0 < K; k0 += 32) {
        gld16(Ag + k0, AsB + tid * 16);
        gld16(Ag + (size_t)64 * K + k0, AsB + 4096 + tid * 16);
        gld16(Bg + k0, BsB + tid * 16);
        gld16(Bg + (size_t)64 * K + k0, BsB + 4096 + tid * 16);
        __syncthreads();

        bf16x8 af[4], bfr[4];
#pragma unroll
        for (int t = 0; t < 4; t++)
            af[t] = *reinterpret_cast<const bf16x8*>(&As[(wm + t * 16 + l15) * 32 + q * 8]);
#pragma unroll
        for (int u = 0; u < 4; u++)
            bfr[u] = *reinterpret_cast<const bf16x8*>(&Bs[(wn + u * 16 + l15) * 32 + q * 8]);
#pragma unroll
        for (int t = 0; t < 4; t++)
#pragma unroll
            for (int u = 0; u < 4; u++)
                acc[t][u] = __builtin_amdgcn_mfma_f32_16x16x32_bf16(af[u == 0 ? t : t], bfr[u], acc[t][u], 0, 0, 0);
        __syncthreads();
    }

    float bias_v[4];
#pragma unroll
    for (int u = 0; u < 4; u++) {
        int gn = n0 + wn + u * 16 + l15;
        bias_v[u] = (gn < Nout) ? bias[gn] : 0.f;
    }

#pragma unroll
    for (int t = 0; t < 4; t++) {
#pragma unroll
        for (int r = 0; r < 4; r++) {
            int gm = m0 + wm + t * 16 + q * 4 + r;
#pragma unroll
            for (int u = 0; u < 4; u++) {
                int gn = n0 + wn + u * 16 + l15;
                if (gn >= Nout) continue;
                float v = acc[t][u][r] + bias_v[u];
                if (EPI == EPI_GELU) {
                    v = 0.5f * v * (1.f + erff(v * 0.70710678118f));
                    if (gm < Mstore) {
                        float ov = (gm < M) ? v : 0.f;
                        ((unsigned short*)C)[(size_t)gm * ldc + gn] = f2bf(ov);
                    }
                } else if (EPI == EPI_VAL) {
                    if (gm < M) {
                        int b = gm / Nl;
                        int nl = gm - b * Nl;
                        size_t orow = (size_t)b * NTOT + loff + nl;
                        ((unsigned short*)C)[orow * ldc + gn] = f2bf(v);
                    }
                } else {
                    if (gm < M) ((float*)C)[(size_t)gm * ldc + gn] = v;
                }
            }
        }
    }
}

// ---------------------------------------------------------------------------
// fp32 -> bf16 cast with row padding (pad region zeroed). 4 elems/thread.
// ---------------------------------------------------------------------------
__launch_bounds__(256)
__global__ void cast_pad_k(const float* __restrict__ X, unsigned short* __restrict__ Y,
                           int melems, int total) {
    int idx = (blockIdx.x * 256 + threadIdx.x) * 4;
    if (idx >= total) return;
    float4 v = make_float4(0.f, 0.f, 0.f, 0.f);
    if (idx < melems) v = *(const float4*)&X[idx];
    ushort4 o;
    o.x = f2bf(v.x); o.y = f2bf(v.y); o.z = f2bf(v.z); o.w = f2bf(v.w);
    *(ushort4*)&Y[idx] = o;
}

// ---------------------------------------------------------------------------
// Weight cast + transpose: W [K,N] fp32 -> Wt [Npad,K] bf16 (zero-pad n>=N).
// ---------------------------------------------------------------------------
__launch_bounds__(256)
__global__ void castw_k(const float* __restrict__ W, unsigned short* __restrict__ Wt,
                        int K, int N, int Npad) {
    int i = blockIdx.x * 256 + threadIdx.x;
    if (i >= Npad * K) return;
    int n = i / K, k = i - n * K;
    float v = (n < N) ? W[(size_t)k * N + n] : 0.f;
    Wt[i] = f2bf(v);
}

// ---------------------------------------------------------------------------
// ref = sigmoid(query @ Wref + bref). One wave per row (fp32 query).
// ---------------------------------------------------------------------------
__launch_bounds__(256)
__global__ void ref_k(const float* __restrict__ Q, const float* __restrict__ Wref,
                      const float* __restrict__ bref, float* __restrict__ refb) {
    int wid = threadIdx.x >> 6;
    int lane = threadIdx.x & 63;
    int row = blockIdx.x * 4 + wid;
    if (row >= MROWS) return;
    float4 qv = *(const float4*)&Q[(size_t)row * DD + lane * 4];
    float4 w01 = *(const float4*)&Wref[lane * 8];
    float4 w23 = *(const float4*)&Wref[lane * 8 + 4];
    float s0 = qv.x * w01.x + qv.y * w01.z + qv.z * w23.x + qv.w * w23.z;
    float s1 = qv.x * w01.y + qv.y * w01.w + qv.z * w23.y + qv.w * w23.w;
#pragma unroll
    for (int m = 32; m >= 1; m >>= 1) {
        s0 += __shfl_xor(s0, m);
        s1 += __shfl_xor(s1, m);
    }
    if (lane == 0) {
        float v0 = s0 + bref[0], v1 = s1 + bref[1];
        refb[(size_t)row * 2 + 0] = 1.f / (1.f + expf(-v0));
        refb[(size_t)row * 2 + 1] = 1.f / (1.f + expf(-v1));
    }
}

// ---------------------------------------------------------------------------
// softmax over groups of 12; fp32 logits in, bf16 out.
// ---------------------------------------------------------------------------
__launch_bounds__(256)
__global__ void softmax12_k(const float* __restrict__ logits, unsigned short* __restrict__ aw) {
    int rh = blockIdx.x * 256 + threadIdx.x;
    if (rh >= MROWS * NHH) return;
    const float* p = logits + (size_t)rh * 12;
    float v[12], mx = -1e30f;
#pragma unroll
    for (int i = 0; i < 12; i++) { v[i] = p[i]; mx = fmaxf(mx, v[i]); }
    float s = 0.f;
#pragma unroll
    for (int i = 0; i < 12; i++) { v[i] = expf(v[i] - mx); s += v[i]; }
    float inv = 1.f / s;
    unsigned short* o = aw + (size_t)rh * 12;
#pragma unroll
    for (int i = 0; i < 12; i++) o[i] = f2bf(v[i] * inv);
}

// ---------------------------------------------------------------------------
// Deformable sampling on bf16 values. 128 threads: tid<96 precompute,
// main loop: h = tid>>4, dim pair = (tid&15)*2, one 4B load per corner.
// ---------------------------------------------------------------------------
__launch_bounds__(128)
__global__ void sample_k(const unsigned short* __restrict__ val, const float* __restrict__ off,
                         const unsigned short* __restrict__ aw, const float* __restrict__ refb,
                         unsigned short* __restrict__ out) {
    const int n = blockIdx.x, b = blockIdx.y;
    const int tid = threadIdx.x;
    __shared__ float sw[96][4];
    __shared__ int sidx[96][4];

    const size_t bn = (size_t)b * NTOT + n;
    if (tid < 96) {
        const int lp = tid % 12;
        const int l = lp >> 2;
        int Hl, Wl, loff;
        if (l == 0)      { Hl = 100; Wl = 100; loff = 0; }
        else if (l == 1) { Hl = 50;  Wl = 50;  loff = 10000; }
        else             { Hl = 25;  Wl = 25;  loff = 12500; }
        float ox = off[bn * 192 + tid * 2 + 0];
        float oy = off[bn * 192 + tid * 2 + 1];
        float a  = bf2f(aw[bn * 96 + tid]);
        float rx = refb[bn * 2 + 0];
        float ry = refb[bn * 2 + 1];
        float x = rx * (float)Wl + ox - 0.5f;
        float y = ry * (float)Hl + oy - 0.5f;
        x = fminf(fmaxf(x, -1e4f), 1e4f);
        y = fminf(fmaxf(y, -1e4f), 1e4f);
        float x0f = floorf(x), y0f = floorf(y);
        float lx = x - x0f, ly = y - y0f;
        int x0 = (int)x0f, y0 = (int)y0f;
#pragma unroll
        for (int c = 0; c < 4; c++) {
            int xi = x0 + (c & 1);
            int yi = y0 + (c >> 1);
            bool ok = (xi >= 0) && (xi < Wl) && (yi >= 0) && (yi < Hl);
            int xc = min(max(xi, 0), Wl - 1);
            int yc = min(max(yi, 0), Hl - 1);
            sidx[tid][c] = b * NTOT + loff + yc * Wl + xc;
            float wgt = ((c & 1) ? lx : 1.f - lx) * ((c >> 1) ? ly : 1.f - ly);
            sw[tid][c] = ok ? a * wgt : 0.f;
        }
    }
    __syncthreads();

    const int h = tid >> 4;
    const int dp = (tid & 15) * 2;
    const unsigned short* vb = val + h * DHH + dp;
    float a0 = 0.f, a1 = 0.f;
#pragma unroll
    for (int lp = 0; lp < 12; lp++) {
        int s = h * 12 + lp;
#pragma unroll
        for (int c = 0; c < 4; c++) {
            float wgt = sw[s][c];
            if (wgt != 0.f) {
                unsigned u = *(const unsigned*)(vb + (size_t)sidx[s][c] * DD);
                a0 += wgt * __uint_as_float(u << 16);
                a1 += wgt * __uint_as_float(u & 0xFFFF0000u);
            }
        }
    }
    unsigned ov = (unsigned)f2bf(a0) | ((unsigned)f2bf(a1) << 16);
    *(unsigned*)(out + bn * DD + h * DHH + dp) = ov;
}

// ---------------------------------------------------------------------------
// out = LN(a + r) * g + be, fp32 out + optional bf16 copy.
// ---------------------------------------------------------------------------
__launch_bounds__(256)
__global__ void addln_k(const float* __restrict__ a, const float* __restrict__ r,
                        const float* __restrict__ g, const float* __restrict__ be,
                        float* __restrict__ out, unsigned short* __restrict__ outb, int wbf) {
    int wid = threadIdx.x >> 6;
    int lane = threadIdx.x & 63;
    int row = blockIdx.x * 4 + wid;
    if (row >= MROWS) return;
    float4 xa = *(const float4*)&a[(size_t)row * DD + lane * 4];
    float4 xr = *(const float4*)&r[(size_t)row * DD + lane * 4];
    float x0 = xa.x + xr.x, x1 = xa.y + xr.y, x2 = xa.z + xr.z, x3 = xa.w + xr.w;
    float s = x0 + x1 + x2 + x3;
    float sq = x0 * x0 + x1 * x1 + x2 * x2 + x3 * x3;
#pragma unroll
    for (int m = 32; m >= 1; m >>= 1) {
        s += __shfl_xor(s, m);
        sq += __shfl_xor(sq, m);
    }
    float mean = s * (1.f / DD);
    float var = sq * (1.f / DD) - mean * mean;
    float rs = rsqrtf(var + EPSLN);
    float4 gg = *(const float4*)&g[lane * 4];
    float4 bb = *(const float4*)&be[lane * 4];
    float4 o;
    o.x = (x0 - mean) * rs * gg.x + bb.x;
    o.y = (x1 - mean) * rs * gg.y + bb.y;
    o.z = (x2 - mean) * rs * gg.z + bb.z;
    o.w = (x3 - mean) * rs * gg.w + bb.w;
    *(float4*)&out[(size_t)row * DD + lane * 4] = o;
    if (wbf) {
        ushort4 ob;
        ob.x = f2bf(o.x); ob.y = f2bf(o.y); ob.z = f2bf(o.z); ob.w = f2bf(o.w);
        *(ushort4*)&outb[(size_t)row * DD + lane * 4] = ob;
    }
}

// ---------------------------------------------------------------------------
extern "C" void kernel_launch(void* const* d_in, const int* in_sizes, int n_in,
                              void* d_out, int out_size, void* d_ws, size_t ws_size,
                              hipStream_t stream) {
    const float* query = (const float*)d_in[0];
    const float* p3    = (const float*)d_in[1];
    const float* p4    = (const float*)d_in[2];
    const float* p5    = (const float*)d_in[3];
    const float* Wv    = (const float*)d_in[4];
    const float* bv    = (const float*)d_in[5];
    const float* Woff  = (const float*)d_in[6];
    const float* boff  = (const float*)d_in[7];
    const float* Wattn = (const float*)d_in[8];
    const float* battn = (const float*)d_in[9];
    const float* Wref  = (const float*)d_in[10];
    const float* bref  = (const float*)d_in[11];
    const float* Wo    = (const float*)d_in[12];
    const float* bo    = (const float*)d_in[13];
    const float* W1    = (const float*)d_in[14];
    const float* b1    = (const float*)d_in[15];
    const float* W2    = (const float*)d_in[16];
    const float* b2    = (const float*)d_in[17];
    const float* g1    = (const float*)d_in[18];
    const float* be1   = (const float*)d_in[19];
    const float* g2    = (const float*)d_in[20];
    const float* be2   = (const float*)d_in[21];
    float* outp = (float*)d_out;

    // ---- workspace layout (bytes), total 213,838,752 ----
    char* wsb = (char*)d_ws;
    unsigned short* qbf    = (unsigned short*)(wsb + 0);            // 52608x256 bf16
    float*          offb   = (float*)(wsb + 26935296);              // 52500x192 f32
    unsigned short* awb    = (unsigned short*)(wsb + 67255296);     // 52500x96 bf16
    float*          refb   = (float*)(wsb + 77335296);              // 52500x2 f32
    char*           regE   = wsb + 77755296;                        // 53,815,296 B
    unsigned short* valb   = (unsigned short*)regE;                 // 52500x256 bf16
    float*          logits = (float*)regE;                          // 52500x96 f32 (pre-Wv)
    float*          qf32   = (float*)regE;                          // 52500x256 f32 (post-Wo)
    unsigned short* sampb  = (unsigned short*)(regE + 26880000);    // 52608x256 bf16
    float*          attnb  = (float*)(wsb + 131570592);             // 52500x256 f32 (-> ffn)
    unsigned short* featsb = (unsigned short*)(wsb + 185330592);    // 52736x256 bf16
    unsigned short* hidb   = featsb;                                // 13184x1024 bf16 (reuse)
    unsigned short* Wtoff  = (unsigned short*)(wsb + 212331424);    // 256x256
    unsigned short* Wtattn = Wtoff + 65536;                         // 128x256
    unsigned short* Wtv    = Wtattn + 32768;                        // 256x256
    unsigned short* Wto    = Wtv + 65536;                           // 256x256
    unsigned short* Wt1    = Wto + 65536;                           // 1024x256
    unsigned short* Wt2    = Wt1 + 262144;                          // 256x1024

    // ---- casts ----
    cast_pad_k<<<dim3((MPAD * 256 / 4 + 255) / 256), 256, 0, stream>>>(
        query, qbf, MROWS * 256, MPAD * 256);
    cast_pad_k<<<dim3((40064 * 256 / 4 + 255) / 256), 256, 0, stream>>>(
        p3, featsb, 40000 * 256, 40064 * 256);
    cast_pad_k<<<dim3((10112 * 256 / 4 + 255) / 256), 256, 0, stream>>>(
        p4, featsb + 40064 * 256, 10000 * 256, 10112 * 256);
    cast_pad_k<<<dim3((2560 * 256 / 4 + 255) / 256), 256, 0, stream>>>(
        p5, featsb + 50176 * 256, 2500 * 256, 2560 * 256);
    castw_k<<<dim3(256), 256, 0, stream>>>(Woff, Wtoff, 256, 192, 256);
    castw_k<<<dim3(128), 256, 0, stream>>>(Wattn, Wtattn, 256, 96, 128);
    castw_k<<<dim3(256), 256, 0, stream>>>(Wv, Wtv, 256, 256, 256);
    castw_k<<<dim3(256), 256, 0, stream>>>(Wo, Wto, 256, 256, 256);
    castw_k<<<dim3(1024), 256, 0, stream>>>(W1, Wt1, 256, 1024, 1024);
    castw_k<<<dim3(1024), 256, 0, stream>>>(W2, Wt2, 1024, 256, 256);

    // ---- query-side projections ----
    mm_k<EPI_PLAIN, float><<<dim3(411, 2), 256, 0, stream>>>(
        qbf, Wtoff, boff, offb, MROWS, 256, 192, 192, 0, 0, 0);
    mm_k<EPI_PLAIN, float><<<dim3(411, 1), 256, 0, stream>>>(
        qbf, Wtattn, battn, logits, MROWS, 256, 96, 96, 0, 0, 0);
    ref_k<<<dim3((MROWS + 3) / 4), 256, 0, stream>>>(query, Wref, bref, refb);
    softmax12_k<<<dim3((MROWS * NHH + 255) / 256), 256, 0, stream>>>(logits, awb);

    // ---- value projection (row-remapped into valb, overwrites logits) ----
    mm_k<EPI_VAL, unsigned short><<<dim3(313, 2), 256, 0, stream>>>(
        featsb, Wtv, bv, valb, 40000, 256, 256, 256, 0, 10000, 0);
    mm_k<EPI_VAL, unsigned short><<<dim3(79, 2), 256, 0, stream>>>(
        featsb + 40064 * 256, Wtv, bv, valb, 10000, 256, 256, 256, 0, 2500, 10000);
    mm_k<EPI_VAL, unsigned short><<<dim3(20, 2), 256, 0, stream>>>(
        featsb + 50176 * 256, Wtv, bv, valb, 2500, 256, 256, 256, 0, 625, 12500);

    // ---- deformable sampling ----
    sample_k<<<dim3(NTOT, BQ), 128, 0, stream>>>(valb, offb, awb, refb, sampb);

    // ---- output projection ----
    mm_k<EPI_PLAIN, float><<<dim3(411, 2), 256, 0, stream>>>(
        sampb, Wto, bo, attnb, MROWS, 256, 256, 256, 0, 0, 0);

    // ---- LN1 (writes qf32 over valb/sampb region + bf16 copy over qbf) ----
    addln_k<<<dim3(MROWS / 4), 256, 0, stream>>>(query, attnb, g1, be1, qf32, qbf, 1);

    // ---- FFN per batch chunk (hid reuses feats region) ----
    for (int b = 0; b < BQ; b++) {
        mm_k<EPI_GELU, unsigned short><<<dim3(103, 8), 256, 0, stream>>>(
            qbf + (size_t)b * NCHUNK * 256, Wt1, b1, hidb,
            NCHUNK, 256, 1024, 1024, NCHUNK_PAD, 0, 0);
        mm_k<EPI_PLAIN, float><<<dim3(103, 2), 256, 0, stream>>>(
            hidb, Wt2, b2, attnb + (size_t)b * NCHUNK * 256,
            NCHUNK, 1024, 256, 256, 0, 0, 0);
    }

    // ---- LN2 -> output ----
    addln_k<<<dim3(MROWS / 4), 256, 0, stream>>>(qf32, attnb, g2, be2, outp, qbf, 0);
}

// Round 4
// 675.833 us; speedup vs baseline: 2.7130x; 1.4356x over previous
//
#include <hip/hip_runtime.h>
#include <math.h>

// Problem constants
#define BQ    4
#define NTOT  13125
#define DD    256
#define NHH   8
#define FFD   1024
#define EPSLN 1e-5f
#define MROWS (BQ * NTOT)        // 52500
#define MPAD  52736              // 412*128
#define NCHUNK 26250             // FFN half
#define NCHUNK_PAD 26368         // 206*128

typedef __bf16 bf16_t;
typedef bf16_t bf16x8 __attribute__((ext_vector_type(8)));
typedef float floatx4 __attribute__((ext_vector_type(4)));

__device__ __forceinline__ unsigned short f2bf(float f) {
    unsigned u = __float_as_uint(f);
    return (unsigned short)((u + 0x7FFFu + ((u >> 16) & 1u)) >> 16);
}
__device__ __forceinline__ float bf2f(unsigned short h) {
    return __uint_as_float(((unsigned)h) << 16);
}

typedef const __attribute__((address_space(1))) unsigned int* gptr_t;
typedef __attribute__((address_space(3))) unsigned int* lptr_t;
__device__ __forceinline__ void gld16(const void* g, void* l) {
    __builtin_amdgcn_global_load_lds((gptr_t)g, (lptr_t)l, 16, 0, 0);
}

enum { EPI_F32 = 0, EPI_BF16 = 1, EPI_GELU = 2, EPI_VALSEG = 3 };

// Map padded concatenated feature row -> value-buffer row (b*NTOT + loff + nl)
__device__ __forceinline__ int val_row(int gm) {
    if (gm < 40064) {
        if (gm >= 40000) return -1;
        int b = gm / 10000; int nl = gm - b * 10000;
        return b * NTOT + nl;
    } else if (gm < 50176) {
        int r = gm - 40064;
        if (r >= 10000) return -1;
        int b = r / 2500; int nl = r - b * 2500;
        return b * NTOT + 10000 + nl;
    } else {
        int r = gm - 50176;
        if (r >= 2500) return -1;
        int b = r / 625; int nl = r - b * 625;
        return b * NTOT + 12500 + nl;
    }
}

// ---------------------------------------------------------------------------
// bf16 MFMA GEMM (m97 structure): A [Mpad,K] bf16, Bt [Npad,K] bf16.
// 128x128 tile, BK=32, 4 waves, 4x4 grid of 16x16x32 mfma.
// ---------------------------------------------------------------------------
template <int EPI, typename OutT>
__launch_bounds__(256)
__global__ void mm_k(const unsigned short* __restrict__ A,
                     const unsigned short* __restrict__ Bt,
                     const float* __restrict__ bias, OutT* __restrict__ C,
                     int M, int K, int Nout, int ldc, int Mstore) {
    __shared__ __align__(16) unsigned short As[128 * 32];
    __shared__ __align__(16) unsigned short Bs[128 * 32];

    const int tid = threadIdx.x;
    const int m0 = blockIdx.x * 128;
    const int n0 = blockIdx.y * 128;
    const int w = tid >> 6, lane = tid & 63;
    const int q = lane >> 4, l15 = lane & 15;
    const int wm = (w & 1) * 64, wn = (w >> 1) * 64;

    const int sr = tid >> 2;
    const int sk = (tid & 3) * 8;

    const unsigned short* Ag = A + (size_t)(m0 + sr) * K + sk;
    const unsigned short* Bg = Bt + (size_t)(n0 + sr) * K + sk;
    char* AsB = (char*)As;
    char* BsB = (char*)Bs;

    floatx4 acc[4][4];
#pragma unroll
    for (int t = 0; t < 4; t++)
#pragma unroll
        for (int u = 0; u < 4; u++) {
            floatx4 z = {0.f, 0.f, 0.f, 0.f};
            acc[t][u] = z;
        }

    for (int k0 = 0; k0 < K; k0 += 32) {
        gld16(Ag + k0, AsB + tid * 16);
        gld16(Ag + (size_t)64 * K + k0, AsB + 4096 + tid * 16);
        gld16(Bg + k0, BsB + tid * 16);
        gld16(Bg + (size_t)64 * K + k0, BsB + 4096 + tid * 16);
        __syncthreads();

        bf16x8 af[4], bfr[4];
#pragma unroll
        for (int t = 0; t < 4; t++)
            af[t] = *reinterpret_cast<const bf16x8*>(&As[(wm + t * 16 + l15) * 32 + q * 8]);
#pragma unroll
        for (int u = 0; u < 4; u++)
            bfr[u] = *reinterpret_cast<const bf16x8*>(&Bs[(wn + u * 16 + l15) * 32 + q * 8]);
#pragma unroll
        for (int t = 0; t < 4; t++)
#pragma unroll
            for (int u = 0; u < 4; u++)
                acc[t][u] = __builtin_amdgcn_mfma_f32_16x16x32_bf16(af[t], bfr[u], acc[t][u], 0, 0, 0);
        __syncthreads();
    }

    float bias_v[4];
#pragma unroll
    for (int u = 0; u < 4; u++) {
        int gn = n0 + wn + u * 16 + l15;
        bias_v[u] = (gn < Nout) ? bias[gn] : 0.f;
    }

#pragma unroll
    for (int t = 0; t < 4; t++) {
#pragma unroll
        for (int r = 0; r < 4; r++) {
            int gm = m0 + wm + t * 16 + q * 4 + r;
            int orow = gm;
            if (EPI == EPI_VALSEG) orow = val_row(gm);
#pragma unroll
            for (int u = 0; u < 4; u++) {
                int gn = n0 + wn + u * 16 + l15;
                if (gn >= Nout) continue;
                float v = acc[t][u][r] + bias_v[u];
                if (EPI == EPI_GELU) {
                    v = 0.5f * v * (1.f + erff(v * 0.70710678118f));
                    if (gm < Mstore) {
                        float ov = (gm < M) ? v : 0.f;
                        ((unsigned short*)C)[(size_t)gm * ldc + gn] = f2bf(ov);
                    }
                } else if (EPI == EPI_VALSEG) {
                    if (orow >= 0)
                        ((unsigned short*)C)[(size_t)orow * ldc + gn] = f2bf(v);
                } else if (EPI == EPI_BF16) {
                    if (gm < M) ((unsigned short*)C)[(size_t)gm * ldc + gn] = f2bf(v);
                } else {
                    if (gm < M) ((float*)C)[(size_t)gm * ldc + gn] = v;
                }
            }
        }
    }
}

// ---------------------------------------------------------------------------
// All activation casts fused: query -> qbf [52736x256], p3/p4/p5 -> featsb
// (padded segments 40064 / 10112 / 2560 rows), pads zeroed. float4 groups.
// ---------------------------------------------------------------------------
#define QELEMS   13500416   // 52736*256
#define F3ELEMS  10256384   // 40064*256
#define F4ELEMS   2588672   // 10112*256
#define TOTELEMS 27000832   // qbf + featsb

__launch_bounds__(256)
__global__ void cast_acts_k(const float* __restrict__ query, const float* __restrict__ p3,
                            const float* __restrict__ p4, const float* __restrict__ p5,
                            unsigned short* __restrict__ qbf, unsigned short* __restrict__ featsb) {
    int idx4 = (blockIdx.x * 256 + threadIdx.x) * 4;
    if (idx4 >= TOTELEMS) return;
    const float* src; unsigned short* dst; int local, real;
    if (idx4 < QELEMS) {
        src = query; dst = qbf; local = idx4; real = 13440000;
    } else {
        int j = idx4 - QELEMS;
        if (j < F3ELEMS)              { src = p3; dst = featsb;                    local = j;            real = 10240000; }
        else if (j < F3ELEMS + F4ELEMS){ src = p4; dst = featsb + F3ELEMS;         local = j - F3ELEMS;  real = 2560000; }
        else                          { src = p5; dst = featsb + F3ELEMS + F4ELEMS; local = j - F3ELEMS - F4ELEMS; real = 640000; }
    }
    float4 v = make_float4(0.f, 0.f, 0.f, 0.f);
    if (local < real) v = *(const float4*)&src[local];
    ushort4 o;
    o.x = f2bf(v.x); o.y = f2bf(v.y); o.z = f2bf(v.z); o.w = f2bf(v.w);
    *(ushort4*)&dst[local] = o;
}

// ---------------------------------------------------------------------------
// All weight preps fused into one arena:
//  Wtq [384][256] (Woff cols|Wattn cols|zero), Wtv [256][256], Wto [256][256],
//  Wt1 [1024][256], Wt2 [256][1024], then biasq[384] f32.
// ---------------------------------------------------------------------------
#define WTQ_E   98304
#define WTV_E   (WTQ_E + 65536)     // 163840
#define WTO_E   (WTV_E + 65536)     // 229376
#define WT1_E   (WTO_E + 262144)    // 491520
#define WT2_E   (WT1_E + 262144)    // 753664
#define PREP_TOT (WT2_E + 384)

__launch_bounds__(256)
__global__ void prep_w_k(const float* __restrict__ Woff, const float* __restrict__ Wattn,
                         const float* __restrict__ Wv, const float* __restrict__ Wo,
                         const float* __restrict__ W1, const float* __restrict__ W2,
                         const float* __restrict__ boff, const float* __restrict__ battn,
                         unsigned short* __restrict__ warena, float* __restrict__ biasq) {
    int i = blockIdx.x * 256 + threadIdx.x;
    if (i >= PREP_TOT) return;
    if (i >= WT2_E) {
        int t = i - WT2_E;
        biasq[t] = (t < 192) ? boff[t] : (t < 288 ? battn[t - 192] : 0.f);
        return;
    }
    float v;
    if (i < WTQ_E) {
        int n = i >> 8, k = i & 255;
        v = (n < 192) ? Woff[k * 192 + n] : (n < 288 ? Wattn[k * 96 + (n - 192)] : 0.f);
    } else if (i < WTV_E) {
        int j = i - WTQ_E; int n = j >> 8, k = j & 255;
        v = Wv[k * 256 + n];
    } else if (i < WTO_E) {
        int j = i - WTV_E; int n = j >> 8, k = j & 255;
        v = Wo[k * 256 + n];
    } else if (i < WT1_E) {
        int j = i - WTO_E; int n = j >> 8, k = j & 255;   // n 0..1023
        v = W1[k * 1024 + n];
    } else {
        int j = i - WT1_E; int n = j >> 10, k = j & 1023;
        v = W2[k * 256 + n];
    }
    warena[i] = f2bf(v);
}

// ---------------------------------------------------------------------------
// ref = sigmoid(query @ Wref + bref). One wave per row (fp32 query).
// ---------------------------------------------------------------------------
__launch_bounds__(256)
__global__ void ref_k(const float* __restrict__ Q, const float* __restrict__ Wref,
                      const float* __restrict__ bref, float* __restrict__ refb) {
    int wid = threadIdx.x >> 6;
    int lane = threadIdx.x & 63;
    int row = blockIdx.x * 4 + wid;
    if (row >= MROWS) return;
    float4 qv = *(const float4*)&Q[(size_t)row * DD + lane * 4];
    float4 w01 = *(const float4*)&Wref[lane * 8];
    float4 w23 = *(const float4*)&Wref[lane * 8 + 4];
    float s0 = qv.x * w01.x + qv.y * w01.z + qv.z * w23.x + qv.w * w23.z;
    float s1 = qv.x * w01.y + qv.y * w01.w + qv.z * w23.y + qv.w * w23.w;
#pragma unroll
    for (int m = 32; m >= 1; m >>= 1) {
        s0 += __shfl_xor(s0, m);
        s1 += __shfl_xor(s1, m);
    }
    if (lane == 0) {
        float v0 = s0 + bref[0], v1 = s1 + bref[1];
        refb[(size_t)row * 2 + 0] = 1.f / (1.f + expf(-v0));
        refb[(size_t)row * 2 + 1] = 1.f / (1.f + expf(-v1));
    }
}

// ---------------------------------------------------------------------------
// softmax over groups of 12 from projb (ldc 288, offset 192) -> bf16 aw.
// ---------------------------------------------------------------------------
__launch_bounds__(256)
__global__ void softmax12_k(const float* __restrict__ projb, unsigned short* __restrict__ aw) {
    int rh = blockIdx.x * 256 + threadIdx.x;
    if (rh >= MROWS * NHH) return;
    int bn = rh >> 3, h = rh & 7;
    const float* p = projb + (size_t)bn * 288 + 192 + h * 12;
    float v[12], mx = -1e30f;
#pragma unroll
    for (int i = 0; i < 12; i++) { v[i] = p[i]; mx = fmaxf(mx, v[i]); }
    float s = 0.f;
#pragma unroll
    for (int i = 0; i < 12; i++) { v[i] = expf(v[i] - mx); s += v[i]; }
    float inv = 1.f / s;
    unsigned short* o = aw + (size_t)rh * 12;
#pragma unroll
    for (int i = 0; i < 12; i++) o[i] = f2bf(v[i] * inv);
}

// ---------------------------------------------------------------------------
// Deformable sampling v3: 64 threads/block, branchless, 8B loads.
// h = tid>>3 (8 heads), dq = (tid&7)*4 (4 dims per thread).
// ---------------------------------------------------------------------------
__launch_bounds__(64)
__global__ void sample_k(const unsigned short* __restrict__ val, const float* __restrict__ off,
                         const unsigned short* __restrict__ aw, const float* __restrict__ refb,
                         unsigned short* __restrict__ out) {
    const int bn = blockIdx.x;
    const int b = bn / NTOT;
    const int tid = threadIdx.x;
    __shared__ float sw[96][4];
    __shared__ int sidx[96][4];

    float rx = refb[(size_t)bn * 2 + 0];
    float ry = refb[(size_t)bn * 2 + 1];
    for (int s0 = tid; s0 < 96; s0 += 64) {
        const int lp = s0 % 12;
        const int l = lp >> 2;
        int Hl, Wl, loff;
        if (l == 0)      { Hl = 100; Wl = 100; loff = 0; }
        else if (l == 1) { Hl = 50;  Wl = 50;  loff = 10000; }
        else             { Hl = 25;  Wl = 25;  loff = 12500; }
        float ox = off[(size_t)bn * 288 + s0 * 2 + 0];
        float oy = off[(size_t)bn * 288 + s0 * 2 + 1];
        float a  = bf2f(aw[(size_t)bn * 96 + s0]);
        float x = rx * (float)Wl + ox - 0.5f;
        float y = ry * (float)Hl + oy - 0.5f;
        x = fminf(fmaxf(x, -1e4f), 1e4f);
        y = fminf(fmaxf(y, -1e4f), 1e4f);
        float x0f = floorf(x), y0f = floorf(y);
        float lx = x - x0f, ly = y - y0f;
        int x0 = (int)x0f, y0 = (int)y0f;
#pragma unroll
        for (int c = 0; c < 4; c++) {
            int xi = x0 + (c & 1);
            int yi = y0 + (c >> 1);
            bool ok = (xi >= 0) && (xi < Wl) && (yi >= 0) && (yi < Hl);
            int xc = min(max(xi, 0), Wl - 1);
            int yc = min(max(yi, 0), Hl - 1);
            sidx[s0][c] = b * NTOT + loff + yc * Wl + xc;
            float wgt = ((c & 1) ? lx : 1.f - lx) * ((c >> 1) ? ly : 1.f - ly);
            sw[s0][c] = ok ? a * wgt : 0.f;
        }
    }
    __syncthreads();

    const int h = tid >> 3;
    const int dq = (tid & 7) * 4;
    const unsigned short* vb = val + h * 32 + dq;
    float a0 = 0.f, a1 = 0.f, a2 = 0.f, a3 = 0.f;
#pragma unroll
    for (int lp = 0; lp < 12; lp++) {
        int s = h * 12 + lp;
#pragma unroll
        for (int c = 0; c < 4; c++) {
            float wgt = sw[s][c];
            uint2 u = *(const uint2*)(vb + (size_t)sidx[s][c] * DD);
            a0 += wgt * __uint_as_float(u.x << 16);
            a1 += wgt * __uint_as_float(u.x & 0xFFFF0000u);
            a2 += wgt * __uint_as_float(u.y << 16);
            a3 += wgt * __uint_as_float(u.y & 0xFFFF0000u);
        }
    }
    uint2 ov;
    ov.x = (unsigned)f2bf(a0) | ((unsigned)f2bf(a1) << 16);
    ov.y = (unsigned)f2bf(a2) | ((unsigned)f2bf(a3) << 16);
    *(uint2*)(out + (size_t)bn * DD + h * 32 + dq) = ov;
}

// ---------------------------------------------------------------------------
// out = LN(a + r) * g + be. RT = residual dtype (float or bf16/ushort).
// ---------------------------------------------------------------------------
template <typename RT, int WBF>
__launch_bounds__(256)
__global__ void addln_k(const float* __restrict__ a, const RT* __restrict__ r,
                        const float* __restrict__ g, const float* __restrict__ be,
                        float* __restrict__ out, unsigned short* __restrict__ outb, int nrows) {
    int wid = threadIdx.x >> 6;
    int lane = threadIdx.x & 63;
    int row = blockIdx.x * 4 + wid;
    if (row >= nrows) return;
    float4 xa = *(const float4*)&a[(size_t)row * DD + lane * 4];
    float x0, x1, x2, x3;
    if (sizeof(RT) == 2) {
        ushort4 rv = *(const ushort4*)((const unsigned short*)r + (size_t)row * DD + lane * 4);
        x0 = xa.x + bf2f(rv.x); x1 = xa.y + bf2f(rv.y);
        x2 = xa.z + bf2f(rv.z); x3 = xa.w + bf2f(rv.w);
    } else {
        float4 rv = *(const float4*)((const float*)r + (size_t)row * DD + lane * 4);
        x0 = xa.x + rv.x; x1 = xa.y + rv.y; x2 = xa.z + rv.z; x3 = xa.w + rv.w;
    }
    float s = x0 + x1 + x2 + x3;
    float sq = x0 * x0 + x1 * x1 + x2 * x2 + x3 * x3;
#pragma unroll
    for (int m = 32; m >= 1; m >>= 1) {
        s += __shfl_xor(s, m);
        sq += __shfl_xor(sq, m);
    }
    float mean = s * (1.f / DD);
    float var = sq * (1.f / DD) - mean * mean;
    float rs = rsqrtf(var + EPSLN);
    float4 gg = *(const float4*)&g[lane * 4];
    float4 bb = *(const float4*)&be[lane * 4];
    float4 o;
    o.x = (x0 - mean) * rs * gg.x + bb.x;
    o.y = (x1 - mean) * rs * gg.y + bb.y;
    o.z = (x2 - mean) * rs * gg.z + bb.z;
    o.w = (x3 - mean) * rs * gg.w + bb.w;
    *(float4*)&out[(size_t)row * DD + lane * 4] = o;
    if (WBF) {
        ushort4 ob;
        ob.x = f2bf(o.x); ob.y = f2bf(o.y); ob.z = f2bf(o.z); ob.w = f2bf(o.w);
        *(ushort4*)&outb[(size_t)row * DD + lane * 4] = ob;
    }
}

// ---------------------------------------------------------------------------
extern "C" void kernel_launch(void* const* d_in, const int* in_sizes, int n_in,
                              void* d_out, int out_size, void* d_ws, size_t ws_size,
                              hipStream_t stream) {
    const float* query = (const float*)d_in[0];
    const float* p3    = (const float*)d_in[1];
    const float* p4    = (const float*)d_in[2];
    const float* p5    = (const float*)d_in[3];
    const float* Wv    = (const float*)d_in[4];
    const float* bv    = (const float*)d_in[5];
    const float* Woff  = (const float*)d_in[6];
    const float* boff  = (const float*)d_in[7];
    const float* Wattn = (const float*)d_in[8];
    const float* battn = (const float*)d_in[9];
    const float* Wref  = (const float*)d_in[10];
    const float* bref  = (const float*)d_in[11];
    const float* Wo    = (const float*)d_in[12];
    const float* bo    = (const float*)d_in[13];
    const float* W1    = (const float*)d_in[14];
    const float* b1    = (const float*)d_in[15];
    const float* W2    = (const float*)d_in[16];
    const float* b2    = (const float*)d_in[17];
    const float* g1    = (const float*)d_in[18];
    const float* be1   = (const float*)d_in[19];
    const float* g2    = (const float*)d_in[20];
    const float* be2   = (const float*)d_in[21];
    float* outp = (float*)d_out;

    // ---- workspace layout (bytes) ----
    char* wsb = (char*)d_ws;
    unsigned short* qbf    = (unsigned short*)(wsb + 0);           // 52736x256 bf16  [0, 27000832)
    float*          projb  = (float*)(wsb + 27000832);             // 52736x288 f32   [27000832, 87752704)
    unsigned short* awb    = (unsigned short*)(wsb + 87752704);    // 52500x96 bf16   [87752704, 97832704)
    float*          refb   = (float*)(wsb + 97832704);             // 52500x2 f32     [97832704, 98252704)
    unsigned short* featsb = (unsigned short*)(wsb + 98252704);    // 52736x256 bf16  [98252704, 125253536)
    unsigned short* valb   = (unsigned short*)(wsb + 125253536);   // 52500x256 bf16  [125253536, 152133536)
    unsigned short* sampb  = (unsigned short*)(wsb + 152133536);   // 52608x256 bf16  [152133536, 179068832)
    unsigned short* warena = (unsigned short*)(wsb + 179068832);   // 753664 bf16     [179068832, 180576160)
    float*          biasq  = (float*)(wsb + 180576160);            // 384 f32
    // aliases (regions dead by the time they're reused):
    unsigned short* attnbf = valb;                                 // Wo out (valb dead after sample)
    float*          qf32   = projb;                                // LN1 out (projb dead after sample/softmax)
    unsigned short* hidb   = awb;                                  // FFN hid chunk 26368x1024 bf16 = 54.0 MB
                                                                   //   spans awb..featsb..valb-start (all dead)
    float*          ffnb   = (float*)(wsb + 141752320);            // 26250x256 f32 chunk (dead sampb/valb tail)

    unsigned short* Wtq = warena;                 // [384][256]
    unsigned short* Wtv = warena + WTQ_E;
    unsigned short* Wto = warena + WTV_E;
    unsigned short* Wt1 = warena + WTO_E;         // [1024][256]
    unsigned short* Wt2 = warena + WT1_E;         // [256][1024]

    // 1) activation casts (query + feats, pads zeroed)
    cast_acts_k<<<dim3(TOTELEMS / 4 / 256), 256, 0, stream>>>(query, p3, p4, p5, qbf, featsb);
    // 2) weight preps
    prep_w_k<<<dim3((PREP_TOT + 255) / 256), 256, 0, stream>>>(
        Woff, Wattn, Wv, Wo, W1, W2, boff, battn, warena, biasq);
    // 3) reference points
    ref_k<<<dim3((MROWS + 3) / 4), 256, 0, stream>>>(query, Wref, bref, refb);
    // 4) combined q projection: [off | attn logits] -> projb [.,288]
    mm_k<EPI_F32, float><<<dim3(MPAD / 128, 3), 256, 0, stream>>>(
        qbf, Wtq, biasq, projb, MROWS, 256, 288, 288, 0);
    // 5) softmax -> aw bf16
    softmax12_k<<<dim3((MROWS * NHH + 255) / 256), 256, 0, stream>>>(projb, awb);
    // 6) value projection (single dispatch, per-row segment remap)
    mm_k<EPI_VALSEG, unsigned short><<<dim3(MPAD / 128, 2), 256, 0, stream>>>(
        featsb, Wtv, bv, valb, 0, 256, 256, 256, 0);
    // 7) deformable sampling
    sample_k<<<dim3(MROWS), 64, 0, stream>>>(valb, projb, awb, refb, sampb);
    // 8) output projection -> attn bf16 (over valb region)
    mm_k<EPI_BF16, unsigned short><<<dim3(52608 / 128, 2), 256, 0, stream>>>(
        sampb, Wto, bo, attnbf, MROWS, 256, 256, 256, 0);
    // 9) LN1: q = LN(query + attn) -> qf32 (projb region) + qbf
    addln_k<unsigned short, 1><<<dim3(MROWS / 4), 256, 0, stream>>>(
        query, attnbf, g1, be1, qf32, qbf, MROWS);
    // 10) FFN in 2 half chunks
    for (int c = 0; c < 2; c++) {
        const unsigned short* qc = qbf + (size_t)c * NCHUNK * DD;
        mm_k<EPI_GELU, unsigned short><<<dim3(NCHUNK_PAD / 128, FFD / 128), 256, 0, stream>>>(
            qc, Wt1, b1, hidb, NCHUNK, 256, FFD, FFD, NCHUNK_PAD);
        mm_k<EPI_F32, float><<<dim3(NCHUNK_PAD / 128, 2), 256, 0, stream>>>(
            hidb, Wt2, b2, ffnb, NCHUNK, FFD, 256, 256, 0);
        addln_k<float, 0><<<dim3((NCHUNK + 3) / 4), 256, 0, stream>>>(
            qf32 + (size_t)c * NCHUNK * DD, ffnb, g2, be2,
            outp + (size_t)c * NCHUNK * DD, (unsigned short*)nullptr, NCHUNK);
    }
}

// Round 5
// 598.556 us; speedup vs baseline: 3.0633x; 1.1291x over previous
//
#include <hip/hip_runtime.h>
#include <math.h>

// Problem constants
#define BQ    4
#define NTOT  13125
#define DD    256
#define NHH   8
#define FFD   1024
#define EPSLN 1e-5f
#define MROWS (BQ * NTOT)        // 52500
#define MPAD  52736              // 412*128

typedef __bf16 bf16_t;
typedef bf16_t bf16x8 __attribute__((ext_vector_type(8)));
typedef float floatx4 __attribute__((ext_vector_type(4)));

__device__ __forceinline__ unsigned short f2bf(float f) {
    unsigned u = __float_as_uint(f);
    return (unsigned short)((u + 0x7FFFu + ((u >> 16) & 1u)) >> 16);
}
__device__ __forceinline__ float bf2f(unsigned short h) {
    return __uint_as_float(((unsigned)h) << 16);
}

typedef const __attribute__((address_space(1))) unsigned int* gptr_t;
typedef __attribute__((address_space(3))) unsigned int* lptr_t;
__device__ __forceinline__ void gld16(const void* g, void* l) {
    __builtin_amdgcn_global_load_lds((gptr_t)g, (lptr_t)l, 16, 0, 0);
}

enum { EPI_F32 = 0, EPI_GELU = 2, EPI_VALSEG = 3 };

// Map padded concatenated feature row -> value-buffer row (b*NTOT + loff + nl)
__device__ __forceinline__ int val_row(int gm) {
    if (gm < 40064) {
        if (gm >= 40000) return -1;
        int b = gm / 10000; int nl = gm - b * 10000;
        return b * NTOT + nl;
    } else if (gm < 50176) {
        int r = gm - 40064;
        if (r >= 10000) return -1;
        int b = r / 2500; int nl = r - b * 2500;
        return b * NTOT + 10000 + nl;
    } else {
        int r = gm - 50176;
        if (r >= 2500) return -1;
        int b = r / 625; int nl = r - b * 625;
        return b * NTOT + 12500 + nl;
    }
}

// ---------------------------------------------------------------------------
// bf16 MFMA GEMM (m97 structure): A [Mpad,K] bf16, Bt [Npad,K] bf16.
// 128x128 tile, BK=32, 4 waves, 4x4 grid of 16x16x32 mfma.
// ---------------------------------------------------------------------------
template <int EPI, typename OutT>
__launch_bounds__(256)
__global__ void mm_k(const unsigned short* __restrict__ A,
                     const unsigned short* __restrict__ Bt,
                     const float* __restrict__ bias, OutT* __restrict__ C,
                     int M, int K, int Nout, int ldc, int Mstore) {
    __shared__ __align__(16) unsigned short As[128 * 32];
    __shared__ __align__(16) unsigned short Bs[128 * 32];

    const int tid = threadIdx.x;
    const int m0 = blockIdx.x * 128;
    const int n0 = blockIdx.y * 128;
    const int w = tid >> 6, lane = tid & 63;
    const int q = lane >> 4, l15 = lane & 15;
    const int wm = (w & 1) * 64, wn = (w >> 1) * 64;

    const int sr = tid >> 2;
    const int sk = (tid & 3) * 8;

    const unsigned short* Ag = A + (size_t)(m0 + sr) * K + sk;
    const unsigned short* Bg = Bt + (size_t)(n0 + sr) * K + sk;
    char* AsB = (char*)As;
    char* BsB = (char*)Bs;

    floatx4 acc[4][4];
#pragma unroll
    for (int t = 0; t < 4; t++)
#pragma unroll
        for (int u = 0; u < 4; u++) {
            floatx4 z = {0.f, 0.f, 0.f, 0.f};
            acc[t][u] = z;
        }

    for (int k0 = 0; k0 < K; k0 += 32) {
        gld16(Ag + k0, AsB + tid * 16);
        gld16(Ag + (size_t)64 * K + k0, AsB + 4096 + tid * 16);
        gld16(Bg + k0, BsB + tid * 16);
        gld16(Bg + (size_t)64 * K + k0, BsB + 4096 + tid * 16);
        __syncthreads();

        bf16x8 af[4], bfr[4];
#pragma unroll
        for (int t = 0; t < 4; t++)
            af[t] = *reinterpret_cast<const bf16x8*>(&As[(wm + t * 16 + l15) * 32 + q * 8]);
#pragma unroll
        for (int u = 0; u < 4; u++)
            bfr[u] = *reinterpret_cast<const bf16x8*>(&Bs[(wn + u * 16 + l15) * 32 + q * 8]);
#pragma unroll
        for (int t = 0; t < 4; t++)
#pragma unroll
            for (int u = 0; u < 4; u++)
                acc[t][u] = __builtin_amdgcn_mfma_f32_16x16x32_bf16(af[t], bfr[u], acc[t][u], 0, 0, 0);
        __syncthreads();
    }

    float bias_v[4];
#pragma unroll
    for (int u = 0; u < 4; u++) {
        int gn = n0 + wn + u * 16 + l15;
        bias_v[u] = (gn < Nout) ? bias[gn] : 0.f;
    }

#pragma unroll
    for (int t = 0; t < 4; t++) {
#pragma unroll
        for (int r = 0; r < 4; r++) {
            int gm = m0 + wm + t * 16 + q * 4 + r;
            int orow = gm;
            if (EPI == EPI_VALSEG) orow = val_row(gm);
#pragma unroll
            for (int u = 0; u < 4; u++) {
                int gn = n0 + wn + u * 16 + l15;
                if (gn >= Nout) continue;
                float v = acc[t][u][r] + bias_v[u];
                if (EPI == EPI_GELU) {
                    v = 0.5f * v * (1.f + erff(v * 0.70710678118f));
                    if (gm < Mstore) {
                        float ov = (gm < M) ? v : 0.f;
                        ((unsigned short*)C)[(size_t)gm * ldc + gn] = f2bf(ov);
                    }
                } else if (EPI == EPI_VALSEG) {
                    if (orow >= 0)
                        ((unsigned short*)C)[(size_t)orow * ldc + gn] = f2bf(v);
                } else {
                    if (gm < M) ((float*)C)[(size_t)gm * ldc + gn] = v;
                }
            }
        }
    }
}

// ---------------------------------------------------------------------------
// Fused GEMM (N=256) + bias + residual + LayerNorm.
// Tile 64 rows x 256 cols (full row), 4 waves col-split 64 each.
// RT: residual dtype (float or ushort/bf16); OT: output (ushort/bf16 or float).
// ---------------------------------------------------------------------------
template <typename RT, typename OT>
__launch_bounds__(256)
__global__ void gemmln_k(const unsigned short* __restrict__ A,
                         const unsigned short* __restrict__ Bt,
                         const float* __restrict__ bias, const RT* __restrict__ res,
                         const float* __restrict__ g, const float* __restrict__ be,
                         OT* __restrict__ out, int M, int K) {
    __shared__ __align__(16) unsigned short As[64 * 32];    // 4 KB
    __shared__ __align__(16) unsigned short Bs[256 * 32];   // 16 KB

    const int tid = threadIdx.x;
    const int m0 = blockIdx.x * 64;
    const int w = tid >> 6, lane = tid & 63;
    const int q = lane >> 4, l15 = lane & 15;
    const int wn = w * 64;

    const int sr = tid >> 2;
    const int sk = (tid & 3) * 8;
    const unsigned short* Ag = A + (size_t)(m0 + sr) * K + sk;
    const unsigned short* Bg = Bt + (size_t)sr * K + sk;
    char* AsB = (char*)As;
    char* BsB = (char*)Bs;

    floatx4 acc[4][4];
#pragma unroll
    for (int t = 0; t < 4; t++)
#pragma unroll
        for (int u = 0; u < 4; u++) {
            floatx4 z = {0.f, 0.f, 0.f, 0.f};
            acc[t][u] = z;
        }

    for (int k0 = 0; k0 < K; k0 += 32) {
        gld16(Ag + k0, AsB + tid * 16);
#pragma unroll
        for (int j = 0; j < 4; j++)
            gld16(Bg + (size_t)j * 64 * K + k0, BsB + j * 4096 + tid * 16);
        __syncthreads();

        bf16x8 af[4], bfr[4];
#pragma unroll
        for (int t = 0; t < 4; t++)
            af[t] = *reinterpret_cast<const bf16x8*>(&As[(t * 16 + l15) * 32 + q * 8]);
#pragma unroll
        for (int u = 0; u < 4; u++)
            bfr[u] = *reinterpret_cast<const bf16x8*>(&Bs[(wn + u * 16 + l15) * 32 + q * 8]);
#pragma unroll
        for (int t = 0; t < 4; t++)
#pragma unroll
            for (int u = 0; u < 4; u++)
                acc[t][u] = __builtin_amdgcn_mfma_f32_16x16x32_bf16(af[t], bfr[u], acc[t][u], 0, 0, 0);
        __syncthreads();
    }
    // after final sync: all LDS frag reads done; reuse As for row stats.

    float gg[4], bb[4], bias_v[4];
#pragma unroll
    for (int u = 0; u < 4; u++) {
        int gn = wn + u * 16 + l15;
        gg[u] = g[gn]; bb[u] = be[gn]; bias_v[u] = bias[gn];
    }

    float x[4][4][4];     // [t][r][u]
    float ssum[4][4], ssq[4][4];
#pragma unroll
    for (int t = 0; t < 4; t++) {
#pragma unroll
        for (int r = 0; r < 4; r++) {
            int gm = m0 + t * 16 + q * 4 + r;
            bool valid = gm < M;
            float s = 0.f, sq = 0.f;
#pragma unroll
            for (int u = 0; u < 4; u++) {
                int gn = wn + u * 16 + l15;
                float rv = 0.f;
                if (valid) {
                    if (sizeof(RT) == 2)
                        rv = bf2f(((const unsigned short*)res)[(size_t)gm * DD + gn]);
                    else
                        rv = ((const float*)res)[(size_t)gm * DD + gn];
                }
                float xx = acc[t][u][r] + bias_v[u] + rv;
                x[t][r][u] = xx;
                s += xx; sq += xx * xx;
            }
            ssum[t][r] = s; ssq[t][r] = sq;
        }
    }
    // reduce over the 16 lanes of each quad (cols within this wave)
#pragma unroll
    for (int m = 1; m <= 8; m <<= 1) {
#pragma unroll
        for (int t = 0; t < 4; t++)
#pragma unroll
            for (int r = 0; r < 4; r++) {
                ssum[t][r] += __shfl_xor(ssum[t][r], m);
                ssq[t][r] += __shfl_xor(ssq[t][r], m);
            }
    }
    // cross-wave reduction via LDS (reuse As region)
    float* Ls = (float*)As;          // [64][4]
    float* Lq = Ls + 256;            // [64][4]
    if (l15 == 0) {
#pragma unroll
        for (int t = 0; t < 4; t++)
#pragma unroll
            for (int r = 0; r < 4; r++) {
                int lr = t * 16 + q * 4 + r;
                Ls[lr * 4 + w] = ssum[t][r];
                Lq[lr * 4 + w] = ssq[t][r];
            }
    }
    __syncthreads();

#pragma unroll
    for (int t = 0; t < 4; t++) {
#pragma unroll
        for (int r = 0; r < 4; r++) {
            int lr = t * 16 + q * 4 + r;
            int gm = m0 + lr;
            float tot = Ls[lr * 4 + 0] + Ls[lr * 4 + 1] + Ls[lr * 4 + 2] + Ls[lr * 4 + 3];
            float totq = Lq[lr * 4 + 0] + Lq[lr * 4 + 1] + Lq[lr * 4 + 2] + Lq[lr * 4 + 3];
            float mean = tot * (1.f / DD);
            float var = totq * (1.f / DD) - mean * mean;
            float rs = rsqrtf(var + EPSLN);
            if (gm < M) {
#pragma unroll
                for (int u = 0; u < 4; u++) {
                    int gn = wn + u * 16 + l15;
                    float o = (x[t][r][u] - mean) * rs * gg[u] + bb[u];
                    if (sizeof(OT) == 2)
                        ((unsigned short*)out)[(size_t)gm * DD + gn] = f2bf(o);
                    else
                        ((float*)out)[(size_t)gm * DD + gn] = o;
                }
            }
        }
    }
}

// ---------------------------------------------------------------------------
// Activation casts fused: query -> qbf [52736x256], p3/p4/p5 -> featsb.
// ---------------------------------------------------------------------------
#define QELEMS   13500416   // 52736*256
#define F3ELEMS  10256384   // 40064*256
#define F4ELEMS   2588672   // 10112*256
#define TOTELEMS 27000832

__launch_bounds__(256)
__global__ void cast_acts_k(const float* __restrict__ query, const float* __restrict__ p3,
                            const float* __restrict__ p4, const float* __restrict__ p5,
                            unsigned short* __restrict__ qbf, unsigned short* __restrict__ featsb) {
    int idx4 = (blockIdx.x * 256 + threadIdx.x) * 4;
    if (idx4 >= TOTELEMS) return;
    const float* src; unsigned short* dst; int local, real;
    if (idx4 < QELEMS) {
        src = query; dst = qbf; local = idx4; real = 13440000;
    } else {
        int j = idx4 - QELEMS;
        if (j < F3ELEMS)              { src = p3; dst = featsb;                    local = j;            real = 10240000; }
        else if (j < F3ELEMS + F4ELEMS){ src = p4; dst = featsb + F3ELEMS;         local = j - F3ELEMS;  real = 2560000; }
        else                          { src = p5; dst = featsb + F3ELEMS + F4ELEMS; local = j - F3ELEMS - F4ELEMS; real = 640000; }
    }
    float4 v = make_float4(0.f, 0.f, 0.f, 0.f);
    if (local < real) v = *(const float4*)&src[local];
    ushort4 o;
    o.x = f2bf(v.x); o.y = f2bf(v.y); o.z = f2bf(v.z); o.w = f2bf(v.w);
    *(ushort4*)&dst[local] = o;
}

// ---------------------------------------------------------------------------
// Weight preps: Wtq [384][256] (Woff|Wattn|Wref|0), Wtv, Wto, Wt1, Wt2,
// then biasq[384] f32 (boff|battn|bref|0).
// ---------------------------------------------------------------------------
#define WTQ_E   98304
#define WTV_E   (WTQ_E + 65536)     // 163840
#define WTO_E   (WTV_E + 65536)     // 229376
#define WT1_E   (WTO_E + 262144)    // 491520
#define WT2_E   (WT1_E + 262144)    // 753664
#define PREP_TOT (WT2_E + 384)

__launch_bounds__(256)
__global__ void prep_w_k(const float* __restrict__ Woff, const float* __restrict__ Wattn,
                         const float* __restrict__ Wref, const float* __restrict__ Wv,
                         const float* __restrict__ Wo, const float* __restrict__ W1,
                         const float* __restrict__ W2, const float* __restrict__ boff,
                         const float* __restrict__ battn, const float* __restrict__ bref,
                         unsigned short* __restrict__ warena, float* __restrict__ biasq) {
    int i = blockIdx.x * 256 + threadIdx.x;
    if (i >= PREP_TOT) return;
    if (i >= WT2_E) {
        int t = i - WT2_E;
        biasq[t] = (t < 192) ? boff[t] : (t < 288 ? battn[t - 192] : (t < 290 ? bref[t - 288] : 0.f));
        return;
    }
    float v;
    if (i < WTQ_E) {
        int n = i >> 8, k = i & 255;
        v = (n < 192) ? Woff[k * 192 + n]
          : (n < 288) ? Wattn[k * 96 + (n - 192)]
          : (n < 290) ? Wref[k * 2 + (n - 288)] : 0.f;
    } else if (i < WTV_E) {
        int j = i - WTQ_E; int n = j >> 8, k = j & 255;
        v = Wv[k * 256 + n];
    } else if (i < WTO_E) {
        int j = i - WTV_E; int n = j >> 8, k = j & 255;
        v = Wo[k * 256 + n];
    } else if (i < WT1_E) {
        int j = i - WTO_E; int n = j >> 8, k = j & 255;
        v = W1[k * 1024 + n];
    } else {
        int j = i - WT1_E; int n = j >> 10, k = j & 1023;
        v = W2[k * 256 + n];
    }
    warena[i] = f2bf(v);
}

// ---------------------------------------------------------------------------
// softmax over groups of 12 from projb (ldc 320, offset 192) -> bf16 aw.
// ---------------------------------------------------------------------------
__launch_bounds__(256)
__global__ void softmax12_k(const float* __restrict__ projb, unsigned short* __restrict__ aw) {
    int rh = blockIdx.x * 256 + threadIdx.x;
    if (rh >= MROWS * NHH) return;
    int bn = rh >> 3, h = rh & 7;
    const float* p = projb + (size_t)bn * 320 + 192 + h * 12;
    float v[12], mx = -1e30f;
#pragma unroll
    for (int i = 0; i < 12; i++) { v[i] = p[i]; mx = fmaxf(mx, v[i]); }
    float s = 0.f;
#pragma unroll
    for (int i = 0; i < 12; i++) { v[i] = expf(v[i] - mx); s += v[i]; }
    float inv = 1.f / s;
    unsigned short* o = aw + (size_t)rh * 12;
#pragma unroll
    for (int i = 0; i < 12; i++) o[i] = f2bf(v[i] * inv);
}

// ---------------------------------------------------------------------------
// Deformable sampling v4: 128 threads = 2 waves, one (b,n) per wave.
// Ref logits read from projb cols 288/289 (sigmoid here). Packed LDS
// {weight, byte-offset} pairs -> one ds_read_b64 per corner.
// ---------------------------------------------------------------------------
__launch_bounds__(128)
__global__ void sample_k(const unsigned short* __restrict__ val, const float* __restrict__ projb,
                         const unsigned short* __restrict__ aw,
                         unsigned short* __restrict__ out) {
    const int wv = threadIdx.x >> 6;
    const int lane = threadIdx.x & 63;
    const int bn = blockIdx.x * 2 + wv;
    const int b = bn / NTOT;
    __shared__ uint2 sc[2][96][4];

    const float* prow = projb + (size_t)bn * 320;
    float rx = 1.f / (1.f + expf(-prow[288]));
    float ry = 1.f / (1.f + expf(-prow[289]));
    for (int s0 = lane; s0 < 96; s0 += 64) {
        const int lp = s0 % 12;
        const int l = lp >> 2;
        int Hl, Wl, loff;
        if (l == 0)      { Hl = 100; Wl = 100; loff = 0; }
        else if (l == 1) { Hl = 50;  Wl = 50;  loff = 10000; }
        else             { Hl = 25;  Wl = 25;  loff = 12500; }
        float ox = prow[s0 * 2 + 0];
        float oy = prow[s0 * 2 + 1];
        float a  = bf2f(aw[(size_t)bn * 96 + s0]);
        float x = rx * (float)Wl + ox - 0.5f;
        float y = ry * (float)Hl + oy - 0.5f;
        x = fminf(fmaxf(x, -1e4f), 1e4f);
        y = fminf(fmaxf(y, -1e4f), 1e4f);
        float x0f = floorf(x), y0f = floorf(y);
        float lx = x - x0f, ly = y - y0f;
        int x0 = (int)x0f, y0 = (int)y0f;
#pragma unroll
        for (int c = 0; c < 4; c++) {
            int xi = x0 + (c & 1);
            int yi = y0 + (c >> 1);
            bool ok = (xi >= 0) && (xi < Wl) && (yi >= 0) && (yi < Hl);
            int xc = min(max(xi, 0), Wl - 1);
            int yc = min(max(yi, 0), Hl - 1);
            int idx = b * NTOT + loff + yc * Wl + xc;
            float wgt = ((c & 1) ? lx : 1.f - lx) * ((c >> 1) ? ly : 1.f - ly);
            sc[wv][s0][c] = make_uint2(__float_as_uint(ok ? a * wgt : 0.f), (unsigned)(idx * 512));
        }
    }
    __syncthreads();

    const int h = lane >> 3;
    const int dq = (lane & 7) * 4;
    const char* vb = (const char*)val + h * 64 + dq * 2;
    float a0 = 0.f, a1 = 0.f, a2 = 0.f, a3 = 0.f;
#pragma unroll
    for (int lp = 0; lp < 12; lp++) {
        int s = h * 12 + lp;
#pragma unroll
        for (int c = 0; c < 4; c++) {
            uint2 p = sc[wv][s][c];
            float wgt = __uint_as_float(p.x);
            uint2 u = *(const uint2*)(vb + p.y);
            a0 += wgt * __uint_as_float(u.x << 16);
            a1 += wgt * __uint_as_float(u.x & 0xFFFF0000u);
            a2 += wgt * __uint_as_float(u.y << 16);
            a3 += wgt * __uint_as_float(u.y & 0xFFFF0000u);
        }
    }
    uint2 ov;
    ov.x = (unsigned)f2bf(a0) | ((unsigned)f2bf(a1) << 16);
    ov.y = (unsigned)f2bf(a2) | ((unsigned)f2bf(a3) << 16);
    *(uint2*)(out + (size_t)bn * DD + h * 32 + dq) = ov;
}

// ---------------------------------------------------------------------------
extern "C" void kernel_launch(void* const* d_in, const int* in_sizes, int n_in,
                              void* d_out, int out_size, void* d_ws, size_t ws_size,
                              hipStream_t stream) {
    const float* query = (const float*)d_in[0];
    const float* p3    = (const float*)d_in[1];
    const float* p4    = (const float*)d_in[2];
    const float* p5    = (const float*)d_in[3];
    const float* Wv    = (const float*)d_in[4];
    const float* bv    = (const float*)d_in[5];
    const float* Woff  = (const float*)d_in[6];
    const float* boff  = (const float*)d_in[7];
    const float* Wattn = (const float*)d_in[8];
    const float* battn = (const float*)d_in[9];
    const float* Wref  = (const float*)d_in[10];
    const float* bref  = (const float*)d_in[11];
    const float* Wo    = (const float*)d_in[12];
    const float* bo    = (const float*)d_in[13];
    const float* W1    = (const float*)d_in[14];
    const float* b1    = (const float*)d_in[15];
    const float* W2    = (const float*)d_in[16];
    const float* b2    = (const float*)d_in[17];
    const float* g1    = (const float*)d_in[18];
    const float* be1   = (const float*)d_in[19];
    const float* g2    = (const float*)d_in[20];
    const float* be2   = (const float*)d_in[21];
    float* outp = (float*)d_out;

    // ---- workspace layout (bytes), total ~186.9 MB ----
    char* wsb = (char*)d_ws;
    unsigned short* qbf    = (unsigned short*)(wsb + 0);           // 52736x256 bf16  [0, 27000832)
    float*          projb  = (float*)(wsb + 27000832);             // 52736x320 f32   [.., 94502912)
    unsigned short* awb    = (unsigned short*)(wsb + 94502912);    // 52500x96 bf16   [.., 104582912)
    unsigned short* featsb = (unsigned short*)(wsb + 104582912);   // 52736x256 bf16  [.., 131583744)
    unsigned short* valb   = (unsigned short*)(wsb + 131583744);   // 52500x256 bf16  [.., 158463744)
    unsigned short* sampb  = (unsigned short*)(wsb + 158463744);   // 52608x256 bf16  [.., 185399296)
    unsigned short* warena = (unsigned short*)(wsb + 185399296);   // 753664 bf16     [.., 186906624)
    float*          biasq  = (float*)(wsb + 186906624);            // 384 f32
    // hid aliases projb+awb+featsb+valb (all dead by W1 time): 108.0 MB needed,
    // region [27000832, 158463744) = 131.5 MB available.
    unsigned short* hidb   = (unsigned short*)(wsb + 27000832);    // 52736x1024 bf16

    unsigned short* Wtq = warena;                 // [384][256]
    unsigned short* Wtv = warena + WTQ_E;
    unsigned short* Wto = warena + WTV_E;
    unsigned short* Wt1 = warena + WTO_E;         // [1024][256]
    unsigned short* Wt2 = warena + WT1_E;         // [256][1024]

    // 1) activation casts
    cast_acts_k<<<dim3(TOTELEMS / 4 / 256), 256, 0, stream>>>(query, p3, p4, p5, qbf, featsb);
    // 2) weight preps (incl. Wref/bref folded into q-proj weight)
    prep_w_k<<<dim3((PREP_TOT + 255) / 256), 256, 0, stream>>>(
        Woff, Wattn, Wref, Wv, Wo, W1, W2, boff, battn, bref, warena, biasq);
    // 3) combined q projection: [off | attn logits | ref logits] -> projb [.,320]
    mm_k<EPI_F32, float><<<dim3(MPAD / 128, 3), 256, 0, stream>>>(
        qbf, Wtq, biasq, projb, MROWS, 256, 290, 320, 0);
    // 4) softmax -> aw bf16
    softmax12_k<<<dim3((MROWS * NHH + 255) / 256), 256, 0, stream>>>(projb, awb);
    // 5) value projection (single dispatch, per-row segment remap)
    mm_k<EPI_VALSEG, unsigned short><<<dim3(MPAD / 128, 2), 256, 0, stream>>>(
        featsb, Wtv, bv, valb, 0, 256, 256, 256, 0);
    // 6) deformable sampling (2 query points per block)
    sample_k<<<dim3(MROWS / 2), 128, 0, stream>>>(valb, projb, awb, sampb);
    // 7) Wo + residual(query f32) + LN1 -> qbf
    gemmln_k<float, unsigned short><<<dim3((MROWS + 63) / 64), 256, 0, stream>>>(
        sampb, Wto, bo, query, g1, be1, qbf, MROWS, 256);
    // 8) W1 + GELU -> hid (pad rows zeroed up to 52736)
    mm_k<EPI_GELU, unsigned short><<<dim3(MPAD / 128, FFD / 128), 256, 0, stream>>>(
        qbf, Wt1, b1, hidb, MROWS, 256, FFD, FFD, MPAD);
    // 9) W2 + residual(qbf bf16) + LN2 -> out f32
    gemmln_k<unsigned short, float><<<dim3((MROWS + 63) / 64), 256, 0, stream>>>(
        hidb, Wt2, b2, qbf, g2, be2, outp, MROWS, 1024);
}